// Round 5
// baseline (746.348 us; speedup 1.0000x reference)
//
#include <hip/hip_runtime.h>

#define NN 128   // points per set
#define NB 128   // batches
#define ND 5     // feature dim
#define INFV 3.4028235e38f
#define ARR_CAP (8 * NN)

__device__ __forceinline__ float wrap_phi(float x) {
  const float PI_F   = 3.14159265358979323846f;
  const float TWO_PI = 6.28318530717958647692f;
  float t = x + PI_F;
  float w = t - floorf(t * (1.0f / TWO_PI)) * TWO_PI;  // jnp.remainder semantics
  return w - PI_F;
}

// DPP fetch with +INF for masked-out/invalid lanes (no-op under fmin)
#define DPP_SRC_INF(x, ctrl, rmask)                                           \
  __int_as_float(__builtin_amdgcn_update_dpp(                                 \
      0x7f800000, __float_as_int(x), (ctrl), (rmask), 0xF, false))

#define DPP_MIN_STEP(x, ctrl, rmask) x = fminf(x, DPP_SRC_INF(x, ctrl, rmask))

// paired (min1,min2) merge step: {x1,x2} <- merge({x1,x2},{partner})
#define DPP_MIN2_STEP(x1, x2, ctrl, rmask)                                    \
  { float _a1 = DPP_SRC_INF(x1, ctrl, rmask);                                 \
    float _a2 = DPP_SRC_INF(x2, ctrl, rmask);                                 \
    float _t  = fmaxf(x1, _a1);                                               \
    x1 = fminf(x1, _a1);                                                      \
    x2 = fminf(fminf(x2, _a2), _t); }

__device__ __forceinline__ int rl_i(int v, int lane) {
  return __builtin_amdgcn_readlane(v, lane);
}
__device__ __forceinline__ float rl_f(float v, int lane) {
  return __int_as_float(__builtin_amdgcn_readlane(__float_as_int(v), lane));
}

__device__ __forceinline__ float wave_min_bcast(float x) {
  DPP_MIN_STEP(x, 0xB1,  0xF);  // quad_perm xor 1
  DPP_MIN_STEP(x, 0x4E,  0xF);  // quad_perm xor 2
  DPP_MIN_STEP(x, 0x141, 0xF);  // row_half_mirror
  DPP_MIN_STEP(x, 0x140, 0xF);  // row_mirror
  DPP_MIN_STEP(x, 0x142, 0xA);  // row_bcast15
  DPP_MIN_STEP(x, 0x143, 0xC);  // row_bcast31 (lane 63 = full min)
  return rl_f(x, 63);
}

// (min1, min2) over all 128 per-lane-pair values; broadcast from lane 63
__device__ __forceinline__ void wave_min2_bcast(float &x1, float &x2) {
  DPP_MIN2_STEP(x1, x2, 0xB1,  0xF);
  DPP_MIN2_STEP(x1, x2, 0x4E,  0xF);
  DPP_MIN2_STEP(x1, x2, 0x141, 0xF);
  DPP_MIN2_STEP(x1, x2, 0x140, 0xF);
  DPP_MIN2_STEP(x1, x2, 0x142, 0xA);
  DPP_MIN2_STEP(x1, x2, 0x143, 0xC);
  x1 = rl_f(x1, 63);
  x2 = rl_f(x2, 63);
}

// One block (64 threads = 1 wave) solves one batch's 128x128 assignment via
// LAPJV: column reduction (fused into cost build) + augmenting row reduction
// + Dijkstra augmentation. Solver state is register-resident; cross-lane via
// DPP / readlane / ballot. LDS: cost matrix + small queues.
__global__ __launch_bounds__(64) void set2set_hungarian(
    const float* __restrict__ inp, const float* __restrict__ tgt,
    float* __restrict__ sums)
{
  const int b = blockIdx.x;
  const int lane = threadIdx.x;

  __shared__ __align__(16) float Csh[NN * NN]; // cost matrix, row-major, 64 KB
  __shared__ float inpS[NN * ND];              // staged input rows
  __shared__ int   rowOwner[NN + 1];           // CR arbitration
  __shared__ float uFree[NN + 1];              // u[] of currently-free rows
  __shared__ int   queue[NN + ARR_CAP + 8];    // free-row work queue

  const float* inB = inp + (size_t)b * NN * ND;
  const float* tgB = tgt + (size_t)b * NN * ND;

  for (int idx = lane; idx < NN * ND; idx += 64) inpS[idx] = inB[idx];
  for (int idx = lane; idx <= NN; idx += 64) { rowOwner[idx] = 0x7fffffff; uFree[idx] = 0.f; }
  __syncthreads();

  // this lane owns 0-indexed columns jA, jB  (1-indexed c1A, c1B)
  const int jA = 2 * lane;
  const int jB = 2 * lane + 1;
  const int c1A = jA + 1, c1B = jB + 1;

  float tA[ND], tB[ND];
  #pragma unroll
  for (int d = 0; d < ND; ++d) { tA[d] = tgB[jA * ND + d]; tB[d] = tgB[jB * ND + d]; }

  // build cost matrix C[i][j] = ||input_i - target_j||, fused column-min (CR)
  float vA = INFV, vB = INFV;  // column duals = column min
  int   rmA = 1,  rmB = 1;     // argmin row (first occurrence, 1-indexed)
  #pragma unroll 4
  for (int i = 0; i < NN; ++i) {
    float sA = 0.f, sB = 0.f;
    #pragma unroll
    for (int d = 0; d < ND; ++d) {
      float x = inpS[i * ND + d];
      float da = x - tA[d]; sA = fmaf(da, da, sA);
      float db = x - tB[d]; sB = fmaf(db, db, sB);
    }
    float cA = sqrtf(sA), cB = sqrtf(sB);
    ((float2*)(Csh + i * NN))[lane] = make_float2(cA, cB);
    if (cA < vA) { vA = cA; rmA = i + 1; }
    if (cB < vB) { vB = cB; rmB = i + 1; }
  }
  __syncthreads();

  // ---- column reduction: greedy match argmin rows, lowest column wins ----
  atomicMin(&rowOwner[rmA], c1A);
  atomicMin(&rowOwner[rmB], c1B);
  __syncthreads();

  int   pA = (rowOwner[rmA] == c1A) ? rmA : 0;  // matched row per column, 0 = free
  int   pB = (rowOwner[rmB] == c1B) ? rmB : 0;
  float uA = 0.f, uB = 0.f;   // dual of the row matched to col A/B
  int   wayA = 0, wayB = 0;

  // free rows -> ordered queue (parallel rank via popcount)
  unsigned long long freeLo = __ballot(rowOwner[1 + lane]  == 0x7fffffff);
  unsigned long long freeHi = __ballot(rowOwner[65 + lane] == 0x7fffffff);
  int nLo = __popcll(freeLo);
  {
    unsigned long long below = freeLo & ((1ull << lane) - 1ull);
    if ((freeLo >> lane) & 1ull) queue[__popcll(below)] = lane + 1;
    unsigned long long belowH = freeHi & ((1ull << lane) - 1ull);
    if ((freeHi >> lane) & 1ull) queue[nLo + __popcll(belowH)] = lane + 65;
  }
  int curQ = 0, tailQ = nLo + __popcll(freeHi);
  __syncthreads();

  // ---- augmenting row reduction (ARR) ----
  int steps = 0;
  while (curQ < tailQ && steps < ARR_CAP) {
    ++steps;
    int i = queue[curQ]; ++curQ;                 // uniform broadcast read
    const float2 c = ((const float2*)(Csh + (i - 1) * NN))[lane];
    float rA = c.x - vA, rB = c.y - vB;          // reduced costs
    float m1 = fminf(rA, rB), m2 = fmaxf(rA, rB);
    wave_min2_bcast(m1, m2);                     // global (min1, min2)

    unsigned long long mA1 = __ballot(rA == m1);
    unsigned long long mB1 = __ballot(rB == m1);
    int l = __ffsll(mA1 | mB1) - 1;
    bool aside = (mA1 >> l) & 1ull;
    int owner = l, slot = aside ? 0 : 1;
    int j1 = 2 * l + (aside ? 1 : 2);

    int i0; float uOld;
    if (slot) { i0 = rl_i(pB, owner); uOld = rl_f(uB, owner); }
    else      { i0 = rl_i(pA, owner); uOld = rl_f(uA, owner); }

    bool lower = (m1 < m2);
    if (lower) {
      float dv = m2 - m1;
      if (lane == owner) { if (slot) vB -= dv; else vA -= dv; }
    } else if (i0 != 0) {
      // tie (m1 == m2): redirect to second-lowest candidate column
      unsigned long long nA = mA1, nB = mB1;
      if (slot) nB &= ~(1ull << l); else nA &= ~(1ull << l);
      unsigned long long msk2 = nA | nB;
      if (msk2) {
        int l2 = __ffsll(msk2) - 1;
        bool aside2 = (nA >> l2) & 1ull;
        owner = l2; slot = aside2 ? 0 : 1;
        j1 = 2 * l2 + (aside2 ? 1 : 2);
        if (slot) { i0 = rl_i(pB, owner); uOld = rl_f(uB, owner); }
        else      { i0 = rl_i(pA, owner); uOld = rl_f(uA, owner); }
      }
    }
    (void)j1;

    // assign row i to the chosen column with u[i] = m2
    if (lane == owner) {
      if (slot) { pB = i; uB = m2; } else { pA = i; uA = m2; }
    }
    if (i0 != 0) {
      if (lane == 0) uFree[i0] = uOld;           // stolen row keeps its dual
      if (lower) { --curQ; queue[curQ] = i0; }   // retry immediately
      else       { queue[tailQ] = i0; ++tailQ; } // defer (tie churn)
    }
  }

  // ---- Dijkstra augmentation for remaining free rows ----
  while (curQ < tailQ) {
    int i = queue[curQ]; ++curQ;
    float uf = uFree[i];

    float mA = INFV, mB = INFV;
    bool usedA = false, usedB = false;
    float ucur = uf;          // u[i] accumulates from its prior dual
    int   j0 = 0, i0 = i;     // p[0] = i
    float ui0 = uf;
    int   jfree = 0;

    for (int guard = 0; guard <= NN + 1; ++guard) {
      usedA |= (j0 == c1A);
      usedB |= (j0 == c1B);
      const float2 c = ((const float2*)(Csh + (i0 - 1) * NN))[lane];
      if (!usedA) { float cur = c.x - ui0 - vA; if (cur < mA) { mA = cur; wayA = j0; } }
      if (!usedB) { float cur = c.y - ui0 - vB; if (cur < mB) { mB = cur; wayB = j0; } }

      // delta = exact min over unused columns (DPP, no LDS)
      float x = fminf(usedA ? INFV : mA, usedB ? INFV : mB);
      float delta = wave_min_bcast(x);

      // argmin column, lowest-index tie-break; evaluated BEFORE -= delta
      unsigned long long mskA = __ballot(!usedA && (mA == delta));
      unsigned long long mskB = __ballot(!usedB && (mB == delta));
      unsigned long long msk  = mskA | mskB;
      int l  = __ffsll(msk) - 1;
      int j1 = 2 * l + 1 + (((mskA >> l) & 1ull) ? 0 : 1);

      // dual updates (registers only)
      ucur += delta;
      if (usedA) { vA -= delta; uA += delta; } else { mA -= delta; }
      if (usedB) { vB -= delta; uB += delta; } else { mB -= delta; }

      // p[j1], u[p[j1]] via uniform readlane
      int owner = (j1 - 1) >> 1, slot = (j1 - 1) & 1;
      int pj1; float upj;
      if (slot) { pj1 = rl_i(pB, owner); upj = rl_f(uB, owner); }
      else      { pj1 = rl_i(pA, owner); upj = rl_f(uA, owner); }
      if (pj1 == 0) { jfree = j1; break; }
      ui0 = upj;
      j0 = j1; i0 = pj1;
    }

    // augment along way[] chain; transfer row + its dual between columns
    int jj = jfree;
    for (int g = 0; g < NN + 1 && jj != 0; ++g) {
      int owner = (jj - 1) >> 1, slot = (jj - 1) & 1;
      int wlo = rl_i(wayA, owner), whi = rl_i(wayB, owner);
      int wj = slot ? whi : wlo;
      int pnew; float unew;
      if (wj == 0) { pnew = i; unew = ucur; }
      else {
        int o2 = (wj - 1) >> 1, s2 = (wj - 1) & 1;
        int plo2 = rl_i(pA, o2), phi2 = rl_i(pB, o2);
        pnew = s2 ? phi2 : plo2;
        float ulo2 = rl_f(uA, o2), uhi2 = rl_f(uB, o2);
        unew = s2 ? uhi2 : ulo2;
      }
      if (lane == owner) {
        if (slot) { pB = pnew; uB = unew; } else { pA = pnew; uA = unew; }
      }
      jj = wj;
    }
  }

  // loss: column j (0-idx) is matched to row r = p-1; d = input[r] - target[j]
  int rA = pA - 1;
  int rB = pB - 1;
  float acc[ND];
  #pragma unroll
  for (int d = 0; d < ND; ++d) {
    float dA = inpS[rA * ND + d] - tA[d];
    float dB = inpS[rB * ND + d] - tB[d];
    if (d == 4) { dA = wrap_phi(dA); dB = wrap_phi(dB); }
    acc[d] = dA * dA + dB * dB;
  }
  #pragma unroll
  for (int d = 0; d < ND; ++d) {
    float s = acc[d];
    #pragma unroll
    for (int off = 32; off > 0; off >>= 1) s += __shfl_xor(s, off);
    if (lane == 0) atomicAdd(&sums[d], s);
  }
}

__global__ void set2set_finalize(const float* __restrict__ sums, float* __restrict__ out) {
  const float inv = 1.0f / (128.0f * 128.0f);
  float x  = sums[0] * inv;
  float y  = sums[1] * inv;
  float E  = sums[2] * inv;
  float th = sums[3] * inv;
  float ph = sums[4] * inv;
  out[1] = x; out[2] = y; out[3] = E; out[4] = th; out[5] = ph;
  out[0] = x + y + E + th + ph;
}

extern "C" void kernel_launch(void* const* d_in, const int* in_sizes, int n_in,
                              void* d_out, int out_size, void* d_ws, size_t ws_size,
                              hipStream_t stream) {
  const float* inp = (const float*)d_in[0];
  const float* tgt = (const float*)d_in[1];
  float* out  = (float*)d_out;
  float* sums = (float*)d_ws;

  hipMemsetAsync(sums, 0, ND * sizeof(float), stream);
  set2set_hungarian<<<dim3(NB), dim3(64), 0, stream>>>(inp, tgt, sums);
  set2set_finalize<<<dim3(1), dim3(1), 0, stream>>>(sums, out);
}

// Round 6
// 462.825 us; speedup vs baseline: 1.6126x; 1.6126x over previous
//
#include <hip/hip_runtime.h>

#define NN 128   // points per set
#define NB 128   // batches
#define ND 5     // feature dim
#define INFV 3.4028235e38f

__device__ __forceinline__ float wrap_phi(float x) {
  const float PI_F   = 3.14159265358979323846f;
  const float TWO_PI = 6.28318530717958647692f;
  float t = x + PI_F;
  float w = t - floorf(t * (1.0f / TWO_PI)) * TWO_PI;  // jnp.remainder semantics
  return w - PI_F;
}

// DPP fetch with +INF for masked-out/invalid lanes (no-op under fmin)
#define DPP_SRC_INF(x, ctrl, rmask)                                           \
  __int_as_float(__builtin_amdgcn_update_dpp(                                 \
      0x7f800000, __float_as_int(x), (ctrl), (rmask), 0xF, false))

#define DPP_MIN_STEP(x, ctrl, rmask) x = fminf(x, DPP_SRC_INF(x, ctrl, rmask))

// paired (min1,min2) merge step: {x1,x2} <- merge({x1,x2},{partner})
#define DPP_MIN2_STEP(x1, x2, ctrl, rmask)                                    \
  { float _a1 = DPP_SRC_INF(x1, ctrl, rmask);                                 \
    float _a2 = DPP_SRC_INF(x2, ctrl, rmask);                                 \
    float _t  = fmaxf(x1, _a1);                                               \
    x1 = fminf(x1, _a1);                                                      \
    x2 = fminf(fminf(x2, _a2), _t); }

__device__ __forceinline__ int rl_i(int v, int lane) {
  return __builtin_amdgcn_readlane(v, lane);
}
__device__ __forceinline__ float rl_f(float v, int lane) {
  return __int_as_float(__builtin_amdgcn_readlane(__float_as_int(v), lane));
}

__device__ __forceinline__ float wave_min_bcast(float x) {
  DPP_MIN_STEP(x, 0xB1,  0xF);  // quad_perm xor 1
  DPP_MIN_STEP(x, 0x4E,  0xF);  // quad_perm xor 2
  DPP_MIN_STEP(x, 0x141, 0xF);  // row_half_mirror
  DPP_MIN_STEP(x, 0x140, 0xF);  // row_mirror
  DPP_MIN_STEP(x, 0x142, 0xA);  // row_bcast15
  DPP_MIN_STEP(x, 0x143, 0xC);  // row_bcast31 (lane 63 = full min)
  return rl_f(x, 63);
}

// (min1, min2) over all 128 per-lane-pair values; broadcast from lane 63
__device__ __forceinline__ void wave_min2_bcast(float &x1, float &x2) {
  DPP_MIN2_STEP(x1, x2, 0xB1,  0xF);
  DPP_MIN2_STEP(x1, x2, 0x4E,  0xF);
  DPP_MIN2_STEP(x1, x2, 0x141, 0xF);
  DPP_MIN2_STEP(x1, x2, 0x140, 0xF);
  DPP_MIN2_STEP(x1, x2, 0x142, 0xA);
  DPP_MIN2_STEP(x1, x2, 0x143, 0xC);
  x1 = rl_f(x1, 63);
  x2 = rl_f(x2, 63);
}

// One block (64 threads = 1 wave) solves one batch's 128x128 assignment:
// column reduction (fused into cost build) + SINGLE-PASS augmenting row
// reduction (no retry -> bounded tail) + Dijkstra augmentation. Solver state
// register-resident; cross-lane via DPP/readlane/ballot; worklists are SGPR
// bitmasks. LDS: cost matrix, staging, uFree.
__global__ __launch_bounds__(64) void set2set_hungarian(
    const float* __restrict__ inp, const float* __restrict__ tgt,
    float* __restrict__ sums)
{
  const int b = blockIdx.x;
  const int lane = threadIdx.x;

  __shared__ __align__(16) float Csh[NN * NN]; // cost matrix, row-major, 64 KB
  __shared__ float inpS[NN * ND];              // staged input rows
  __shared__ int   rowOwner[NN + 1];           // CR arbitration
  __shared__ float uFree[NN + 1];              // u[] of rows freed by steals

  const float* inB = inp + (size_t)b * NN * ND;
  const float* tgB = tgt + (size_t)b * NN * ND;

  for (int idx = lane; idx < NN * ND; idx += 64) inpS[idx] = inB[idx];
  for (int idx = lane; idx <= NN; idx += 64) { rowOwner[idx] = 0x7fffffff; uFree[idx] = 0.f; }
  __syncthreads();

  // this lane owns 0-indexed columns jA, jB  (1-indexed c1A, c1B)
  const int jA = 2 * lane;
  const int jB = 2 * lane + 1;
  const int c1A = jA + 1, c1B = jB + 1;

  float tA[ND], tB[ND];
  #pragma unroll
  for (int d = 0; d < ND; ++d) { tA[d] = tgB[jA * ND + d]; tB[d] = tgB[jB * ND + d]; }

  // build cost matrix C[i][j] = ||input_i - target_j||, fused column-min (CR)
  float vA = INFV, vB = INFV;  // column duals = column min
  int   rmA = 1,  rmB = 1;     // argmin row (first occurrence, 1-indexed)
  #pragma unroll 4
  for (int i = 0; i < NN; ++i) {
    float sA = 0.f, sB = 0.f;
    #pragma unroll
    for (int d = 0; d < ND; ++d) {
      float x = inpS[i * ND + d];
      float da = x - tA[d]; sA = fmaf(da, da, sA);
      float db = x - tB[d]; sB = fmaf(db, db, sB);
    }
    float cA = sqrtf(sA), cB = sqrtf(sB);
    ((float2*)(Csh + i * NN))[lane] = make_float2(cA, cB);
    if (cA < vA) { vA = cA; rmA = i + 1; }
    if (cB < vB) { vB = cB; rmB = i + 1; }
  }
  __syncthreads();

  // ---- column reduction: greedy match argmin rows, lowest column wins ----
  atomicMin(&rowOwner[rmA], c1A);
  atomicMin(&rowOwner[rmB], c1B);
  __syncthreads();

  int   pA = (rowOwner[rmA] == c1A) ? rmA : 0;  // matched row per column, 0 = free
  int   pB = (rowOwner[rmB] == c1B) ? rmB : 0;
  float uA = 0.f, uB = 0.f;   // dual of the row matched to col A/B
  int   wayA = 0, wayB = 0;

  // free-row bitmasks (wave-uniform)
  unsigned long long remLo = __ballot(rowOwner[1 + lane]  == 0x7fffffff);
  unsigned long long remHi = __ballot(rowOwner[65 + lane] == 0x7fffffff);
  unsigned long long dijLo = 0ull, dijHi = 0ull;  // rows for Dijkstra phase

  // ---- single-pass augmenting row reduction (each free row exactly once) ----
  while (remLo | remHi) {
    int i;
    if (remLo) { int t = __ffsll(remLo) - 1; remLo &= remLo - 1ull; i = t + 1; }
    else       { int t = __ffsll(remHi) - 1; remHi &= remHi - 1ull; i = t + 65; }

    const float2 c = ((const float2*)(Csh + (i - 1) * NN))[lane];
    float rcA = c.x - vA, rcB = c.y - vB;        // reduced costs (u[i] = 0)
    float m1 = fminf(rcA, rcB), m2 = fmaxf(rcA, rcB);
    wave_min2_bcast(m1, m2);                     // global (min1, min2)

    unsigned long long mA1 = __ballot(rcA == m1);
    unsigned long long mB1 = __ballot(rcB == m1);
    int l = __ffsll(mA1 | mB1) - 1;
    bool aside = (mA1 >> l) & 1ull;
    int owner = l;
    int slot = aside ? 0 : 1;

    int   pSel = slot ? pB : pA;                 // uniform-cond select
    float uSel = slot ? uB : uA;
    int   i0   = rl_i(pSel, owner);              // current occupant (0 = free)
    float uOld = rl_f(uSel, owner);

    float dv = m2 - m1;                          // >= 0
    bool selA = (lane == owner) && (slot == 0);
    bool selB = (lane == owner) && (slot == 1);
    vA -= selA ? dv : 0.f;   vB -= selB ? dv : 0.f;
    pA  = selA ? i  : pA;    pB  = selB ? i  : pB;
    uA  = selA ? m2 : uA;    uB  = selB ? m2 : uB;

    if (i0 != 0) {                               // stolen row -> Dijkstra
      if (lane == 0) uFree[i0] = uOld;
      if (i0 <= 64) dijLo |= 1ull << (i0 - 1);
      else          dijHi |= 1ull << (i0 - 65);
    }
  }

  // ---- Dijkstra augmentation for remaining free rows ----
  while (dijLo | dijHi) {
    int i;
    if (dijLo) { int t = __ffsll(dijLo) - 1; dijLo &= dijLo - 1ull; i = t + 1; }
    else       { int t = __ffsll(dijHi) - 1; dijHi &= dijHi - 1ull; i = t + 65; }
    float uf = uFree[i];

    float mA = INFV, mB = INFV;
    bool usedA = false, usedB = false;
    float ucur = uf;          // u[i] accumulates from its prior dual
    int   j0 = 0, i0 = i;     // p[0] = i
    float ui0 = uf;
    int   jfree = 0;

    for (int guard = 0; guard <= NN + 1; ++guard) {
      usedA |= (j0 == c1A);
      usedB |= (j0 == c1B);
      const float2 c = ((const float2*)(Csh + (i0 - 1) * NN))[lane];
      float curA = c.x - ui0 - vA;
      float curB = c.y - ui0 - vB;
      bool updA = !usedA && (curA < mA);
      bool updB = !usedB && (curB < mB);
      mA = updA ? curA : mA;  wayA = updA ? j0 : wayA;
      mB = updB ? curB : mB;  wayB = updB ? j0 : wayB;

      // delta = exact min over unused columns (DPP, no LDS)
      float x = fminf(usedA ? INFV : mA, usedB ? INFV : mB);
      float delta = wave_min_bcast(x);

      // argmin column, lowest-index tie-break; evaluated BEFORE -= delta
      unsigned long long mskA = __ballot(!usedA && (mA == delta));
      unsigned long long mskB = __ballot(!usedB && (mB == delta));
      unsigned long long msk  = mskA | mskB;
      int l = __ffsll(msk) - 1;
      bool aside = (mskA >> l) & 1ull;
      int owner = l;
      int slot  = aside ? 0 : 1;
      int j1 = 2 * l + 1 + slot;

      // branchless dual updates
      ucur += delta;
      float dA = usedA ? delta : 0.f;
      float dB = usedB ? delta : 0.f;
      vA -= dA; uA += dA; mA -= (delta - dA);
      vB -= dB; uB += dB; mB -= (delta - dB);

      // p[j1], u[p[j1]]: uniform slot-select then single readlane each
      int   pSel = slot ? pB : pA;
      float uSel = slot ? uB : uA;
      int pj1 = rl_i(pSel, owner);
      if (pj1 == 0) { jfree = j1; break; }
      ui0 = rl_f(uSel, owner);
      j0 = j1; i0 = pj1;
    }

    // augment along way[] chain; transfer row + its dual between columns
    int jj = jfree;
    for (int g = 0; g < NN + 1 && jj != 0; ++g) {
      int owner = (jj - 1) >> 1, slot = (jj - 1) & 1;
      int wSel = slot ? rl_i(wayB, owner) : rl_i(wayA, owner);
      int wj = wSel;
      int pnew; float unew;
      if (wj == 0) { pnew = i; unew = ucur; }
      else {
        int o2 = (wj - 1) >> 1, s2 = (wj - 1) & 1;
        int   pS2 = s2 ? rl_i(pB, o2) : rl_i(pA, o2);
        float uS2 = s2 ? rl_f(uB, o2) : rl_f(uA, o2);
        pnew = pS2; unew = uS2;
      }
      bool selA = (lane == owner) && (slot == 0);
      bool selB = (lane == owner) && (slot == 1);
      pA = selA ? pnew : pA;  uA = selA ? unew : uA;
      pB = selB ? pnew : pB;  uB = selB ? unew : uB;
      jj = wj;
    }
  }

  // loss: column j (0-idx) is matched to row r = p-1; d = input[r] - target[j]
  int rA = pA - 1;
  int rB = pB - 1;
  float acc[ND];
  #pragma unroll
  for (int d = 0; d < ND; ++d) {
    float dA = inpS[rA * ND + d] - tA[d];
    float dB = inpS[rB * ND + d] - tB[d];
    if (d == 4) { dA = wrap_phi(dA); dB = wrap_phi(dB); }
    acc[d] = dA * dA + dB * dB;
  }
  #pragma unroll
  for (int d = 0; d < ND; ++d) {
    float s = acc[d];
    #pragma unroll
    for (int off = 32; off > 0; off >>= 1) s += __shfl_xor(s, off);
    if (lane == 0) atomicAdd(&sums[d], s);
  }
}

__global__ void set2set_finalize(const float* __restrict__ sums, float* __restrict__ out) {
  const float inv = 1.0f / (128.0f * 128.0f);
  float x  = sums[0] * inv;
  float y  = sums[1] * inv;
  float E  = sums[2] * inv;
  float th = sums[3] * inv;
  float ph = sums[4] * inv;
  out[1] = x; out[2] = y; out[3] = E; out[4] = th; out[5] = ph;
  out[0] = x + y + E + th + ph;
}

extern "C" void kernel_launch(void* const* d_in, const int* in_sizes, int n_in,
                              void* d_out, int out_size, void* d_ws, size_t ws_size,
                              hipStream_t stream) {
  const float* inp = (const float*)d_in[0];
  const float* tgt = (const float*)d_in[1];
  float* out  = (float*)d_out;
  float* sums = (float*)d_ws;

  hipMemsetAsync(sums, 0, ND * sizeof(float), stream);
  set2set_hungarian<<<dim3(NB), dim3(64), 0, stream>>>(inp, tgt, sums);
  set2set_finalize<<<dim3(1), dim3(1), 0, stream>>>(sums, out);
}

// Round 7
// 402.275 us; speedup vs baseline: 1.8553x; 1.1505x over previous
//
#include <hip/hip_runtime.h>

#define NN 128   // points per set
#define NB 128   // batches
#define ND 5     // feature dim
#define INFV 3.4028235e38f

__device__ __forceinline__ float wrap_phi(float x) {
  const float PI_F   = 3.14159265358979323846f;
  const float TWO_PI = 6.28318530717958647692f;
  float t = x + PI_F;
  float w = t - floorf(t * (1.0f / TWO_PI)) * TWO_PI;  // jnp.remainder semantics
  return w - PI_F;
}

// DPP fetch with +INF for masked-out/invalid lanes (no-op under fmin)
#define DPP_SRC_INF(x, ctrl, rmask)                                           \
  __int_as_float(__builtin_amdgcn_update_dpp(                                 \
      0x7f800000, __float_as_int(x), (ctrl), (rmask), 0xF, false))

#define DPP_MIN_STEP(x, ctrl, rmask) x = fminf(x, DPP_SRC_INF(x, ctrl, rmask))

// paired (min1,min2) merge step: {x1,x2} <- merge({x1,x2},{partner})
#define DPP_MIN2_STEP(x1, x2, ctrl, rmask)                                    \
  { float _a1 = DPP_SRC_INF(x1, ctrl, rmask);                                 \
    float _a2 = DPP_SRC_INF(x2, ctrl, rmask);                                 \
    float _t  = fmaxf(x1, _a1);                                               \
    x1 = fminf(x1, _a1);                                                      \
    x2 = fminf(fminf(x2, _a2), _t); }

__device__ __forceinline__ int rl_i(int v, int lane) {
  return __builtin_amdgcn_readlane(v, lane);
}
__device__ __forceinline__ float rl_f(float v, int lane) {
  return __int_as_float(__builtin_amdgcn_readlane(__float_as_int(v), lane));
}

__device__ __forceinline__ float wave_min_bcast(float x) {
  DPP_MIN_STEP(x, 0xB1,  0xF);  // quad_perm xor 1
  DPP_MIN_STEP(x, 0x4E,  0xF);  // quad_perm xor 2
  DPP_MIN_STEP(x, 0x141, 0xF);  // row_half_mirror
  DPP_MIN_STEP(x, 0x140, 0xF);  // row_mirror
  DPP_MIN_STEP(x, 0x142, 0xA);  // row_bcast15
  DPP_MIN_STEP(x, 0x143, 0xC);  // row_bcast31 (lane 63 = full min)
  return rl_f(x, 63);
}

// (min1, min2) over all 128 per-lane-pair values; broadcast from lane 63
__device__ __forceinline__ void wave_min2_bcast(float &x1, float &x2) {
  DPP_MIN2_STEP(x1, x2, 0xB1,  0xF);
  DPP_MIN2_STEP(x1, x2, 0x4E,  0xF);
  DPP_MIN2_STEP(x1, x2, 0x141, 0xF);
  DPP_MIN2_STEP(x1, x2, 0x140, 0xF);
  DPP_MIN2_STEP(x1, x2, 0x142, 0xA);
  DPP_MIN2_STEP(x1, x2, 0x143, 0xC);
  x1 = rl_f(x1, 63);
  x2 = rl_f(x2, 63);
}

// One block (64 threads = 1 wave) solves one batch's 128x128 assignment:
// full LAPJV init (column reduction fused into cost build + reduction
// transfer + 2-pass augmenting row reduction, all strictly bounded) +
// Dijkstra augmentation. Solver state register-resident; cross-lane via
// DPP/readlane/ballot; worklists are SGPR bitmasks.
__global__ __launch_bounds__(64) void set2set_hungarian(
    const float* __restrict__ inp, const float* __restrict__ tgt,
    float* __restrict__ sums)
{
  const int b = blockIdx.x;
  const int lane = threadIdx.x;

  __shared__ __align__(16) float Csh[NN * NN]; // cost matrix, row-major, 64 KB
  __shared__ float inpS[NN * ND];              // staged input rows
  __shared__ int   rowOwner[NN + 1];           // CR arbitration
  __shared__ float uFree[NN + 1];              // u[] of rows freed by steals

  const float* inB = inp + (size_t)b * NN * ND;
  const float* tgB = tgt + (size_t)b * NN * ND;

  for (int idx = lane; idx < NN * ND; idx += 64) inpS[idx] = inB[idx];
  for (int idx = lane; idx <= NN; idx += 64) { rowOwner[idx] = 0x7fffffff; uFree[idx] = 0.f; }
  __syncthreads();

  // this lane owns 0-indexed columns jA, jB  (1-indexed c1A, c1B)
  const int jA = 2 * lane;
  const int jB = 2 * lane + 1;
  const int c1A = jA + 1, c1B = jB + 1;

  float tA[ND], tB[ND];
  #pragma unroll
  for (int d = 0; d < ND; ++d) { tA[d] = tgB[jA * ND + d]; tB[d] = tgB[jB * ND + d]; }

  // build cost matrix C[i][j] = ||input_i - target_j||, fused column-min (CR)
  float vA = INFV, vB = INFV;  // column duals = column min
  int   rmA = 1,  rmB = 1;     // argmin row (first occurrence, 1-indexed)
  #pragma unroll 4
  for (int i = 0; i < NN; ++i) {
    float sA = 0.f, sB = 0.f;
    #pragma unroll
    for (int d = 0; d < ND; ++d) {
      float x = inpS[i * ND + d];
      float da = x - tA[d]; sA = fmaf(da, da, sA);
      float db = x - tB[d]; sB = fmaf(db, db, sB);
    }
    float cA = sqrtf(sA), cB = sqrtf(sB);
    ((float2*)(Csh + i * NN))[lane] = make_float2(cA, cB);
    if (cA < vA) { vA = cA; rmA = i + 1; }
    if (cB < vB) { vB = cB; rmB = i + 1; }
  }
  __syncthreads();

  // ---- column reduction: greedy match argmin rows, lowest column wins ----
  atomicMin(&rowOwner[rmA], c1A);
  atomicMin(&rowOwner[rmB], c1B);
  __syncthreads();

  int   pA = (rowOwner[rmA] == c1A) ? rmA : 0;  // matched row per column, 0 = free
  int   pB = (rowOwner[rmB] == c1B) ? rmB : 0;
  float uA = 0.f, uB = 0.f;   // dual of the row matched to col A/B
  int   wayA = 0, wayB = 0;

  // ---- reduction transfer: tighten v for every CR-matched column ----
  {
    unsigned long long mtA = __ballot(pA != 0);
    unsigned long long mtB = __ballot(pB != 0);
    while (mtA | mtB) {
      int l, slot;
      if (mtA) { l = __ffsll(mtA) - 1; mtA &= mtA - 1ull; slot = 0; }
      else     { l = __ffsll(mtB) - 1; mtB &= mtB - 1ull; slot = 1; }
      int owner = l;
      int i = rl_i(slot ? pB : pA, owner);       // matched row (uniform)
      const float2 c = ((const float2*)(Csh + (i - 1) * NN))[lane];
      float rA_ = c.x - vA, rB_ = c.y - vB;
      if (lane == owner) { if (slot) rB_ = INFV; else rA_ = INFV; }  // exclude j1
      float mu = wave_min_bcast(fminf(rA_, rB_));
      bool selA = (lane == owner) && (slot == 0);
      bool selB = (lane == owner) && (slot == 1);
      vA -= selA ? mu : 0.f;   vB -= selB ? mu : 0.f;
      uA  = selA ? mu : uA;    uB  = selB ? mu : uB;
    }
  }

  // free rows after CR
  unsigned long long remLo = __ballot(rowOwner[1 + lane]  == 0x7fffffff);
  unsigned long long remHi = __ballot(rowOwner[65 + lane] == 0x7fffffff);
  unsigned long long dijLo = 0ull, dijHi = 0ull;

  // ---- augmenting row reduction: 2 bounded passes (no within-pass retry) ----
  #pragma unroll 1
  for (int pass = 0; pass < 2; ++pass) {
    unsigned long long inLo = remLo, inHi = remHi;
    unsigned long long outLo = 0ull, outHi = 0ull;
    while (inLo | inHi) {
      int i;
      if (inLo) { int t = __ffsll(inLo) - 1; inLo &= inLo - 1ull; i = t + 1; }
      else      { int t = __ffsll(inHi) - 1; inHi &= inHi - 1ull; i = t + 65; }

      const float2 c = ((const float2*)(Csh + (i - 1) * NN))[lane];
      float rcA = c.x - vA, rcB = c.y - vB;      // reduced costs (u recomputed)
      float m1 = fminf(rcA, rcB), m2 = fmaxf(rcA, rcB);
      float candv = m1;
      int   candc = (rcA <= rcB) ? c1A : c1B;    // lane-local argmin col
      wave_min2_bcast(m1, m2);                   // global (min1, min2)

      unsigned long long msk = __ballot(candv == m1);
      int l = __ffsll(msk) - 1;                  // lowest lane = lowest column
      int j1 = rl_i(candc, l);
      int owner = l, slot = (j1 - 1) & 1;

      int   i0   = rl_i(slot ? pB : pA, owner);  // current occupant (0 = free)
      float uOld = rl_f(slot ? uB : uA, owner);

      float dv = m2 - m1;                        // >= 0
      bool selA = (lane == owner) && (slot == 0);
      bool selB = (lane == owner) && (slot == 1);
      vA -= selA ? dv : 0.f;   vB -= selB ? dv : 0.f;
      pA  = selA ? i  : pA;    pB  = selB ? i  : pB;
      uA  = selA ? m2 : uA;    uB  = selB ? m2 : uB;

      if (i0 != 0) {                             // stolen row -> next phase
        if (lane == 0) uFree[i0] = uOld;
        if (i0 <= 64) outLo |= 1ull << (i0 - 1);
        else          outHi |= 1ull << (i0 - 65);
      }
    }
    remLo = outLo; remHi = outHi;
  }
  dijLo = remLo; dijHi = remHi;

  // ---- Dijkstra augmentation for remaining free rows ----
  while (dijLo | dijHi) {
    int i;
    if (dijLo) { int t = __ffsll(dijLo) - 1; dijLo &= dijLo - 1ull; i = t + 1; }
    else       { int t = __ffsll(dijHi) - 1; dijHi &= dijHi - 1ull; i = t + 65; }
    float uf = uFree[i];

    float mA = INFV, mB = INFV;
    bool usedA = false, usedB = false;
    float ucur = uf;          // u[i] accumulates from its prior dual
    int   j0 = 0, i0 = i;     // p[0] = i
    float ui0 = uf;
    int   jfree = 0;

    for (int guard = 0; guard <= NN + 1; ++guard) {
      usedA |= (j0 == c1A);
      usedB |= (j0 == c1B);
      const float2 c = ((const float2*)(Csh + (i0 - 1) * NN))[lane];
      float curA = c.x - ui0 - vA;
      float curB = c.y - ui0 - vB;
      bool updA = !usedA && (curA < mA);
      bool updB = !usedB && (curB < mB);
      mA = updA ? curA : mA;  wayA = updA ? j0 : wayA;
      mB = updB ? curB : mB;  wayB = updB ? j0 : wayB;

      // delta + argmin col (lowest-index tie-break), 1 ballot + 1 readlane
      float mAx = usedA ? INFV : mA;
      float mBx = usedB ? INFV : mB;
      float candv = fminf(mAx, mBx);
      int   candc = (mAx <= mBx) ? c1A : c1B;
      float delta = wave_min_bcast(candv);
      unsigned long long msk = __ballot(candv == delta);
      int l = __ffsll(msk) - 1;
      int j1 = rl_i(candc, l);
      int owner = l, slot = (j1 - 1) & 1;

      // branchless dual updates
      ucur += delta;
      float dA = usedA ? delta : 0.f;
      float dB = usedB ? delta : 0.f;
      vA -= dA; uA += dA; mA -= (delta - dA);
      vB -= dB; uB += dB; mB -= (delta - dB);

      // p[j1], u[p[j1]]: uniform slot-select then single readlane each
      int pj1 = rl_i(slot ? pB : pA, owner);
      if (pj1 == 0) { jfree = j1; break; }
      ui0 = rl_f(slot ? uB : uA, owner);
      j0 = j1; i0 = pj1;
    }

    // augment along way[] chain; transfer row + its dual between columns
    int jj = jfree;
    for (int g = 0; g < NN + 1 && jj != 0; ++g) {
      int owner = (jj - 1) >> 1, slot = (jj - 1) & 1;
      int wj = slot ? rl_i(wayB, owner) : rl_i(wayA, owner);
      int pnew; float unew;
      if (wj == 0) { pnew = i; unew = ucur; }
      else {
        int o2 = (wj - 1) >> 1, s2 = (wj - 1) & 1;
        pnew = s2 ? rl_i(pB, o2) : rl_i(pA, o2);
        unew = s2 ? rl_f(uB, o2) : rl_f(uA, o2);
      }
      bool selA = (lane == owner) && (slot == 0);
      bool selB = (lane == owner) && (slot == 1);
      pA = selA ? pnew : pA;  uA = selA ? unew : uA;
      pB = selB ? pnew : pB;  uB = selB ? unew : uB;
      jj = wj;
    }
  }

  // loss: column j (0-idx) is matched to row r = p-1; d = input[r] - target[j]
  int rA = pA - 1;
  int rB = pB - 1;
  float acc[ND];
  #pragma unroll
  for (int d = 0; d < ND; ++d) {
    float dA = inpS[rA * ND + d] - tA[d];
    float dB = inpS[rB * ND + d] - tB[d];
    if (d == 4) { dA = wrap_phi(dA); dB = wrap_phi(dB); }
    acc[d] = dA * dA + dB * dB;
  }
  #pragma unroll
  for (int d = 0; d < ND; ++d) {
    float s = acc[d];
    #pragma unroll
    for (int off = 32; off > 0; off >>= 1) s += __shfl_xor(s, off);
    if (lane == 0) atomicAdd(&sums[d], s);
  }
}

__global__ void set2set_finalize(const float* __restrict__ sums, float* __restrict__ out) {
  const float inv = 1.0f / (128.0f * 128.0f);
  float x  = sums[0] * inv;
  float y  = sums[1] * inv;
  float E  = sums[2] * inv;
  float th = sums[3] * inv;
  float ph = sums[4] * inv;
  out[1] = x; out[2] = y; out[3] = E; out[4] = th; out[5] = ph;
  out[0] = x + y + E + th + ph;
}

extern "C" void kernel_launch(void* const* d_in, const int* in_sizes, int n_in,
                              void* d_out, int out_size, void* d_ws, size_t ws_size,
                              hipStream_t stream) {
  const float* inp = (const float*)d_in[0];
  const float* tgt = (const float*)d_in[1];
  float* out  = (float*)d_out;
  float* sums = (float*)d_ws;

  hipMemsetAsync(sums, 0, ND * sizeof(float), stream);
  set2set_hungarian<<<dim3(NB), dim3(64), 0, stream>>>(inp, tgt, sums);
  set2set_finalize<<<dim3(1), dim3(1), 0, stream>>>(sums, out);
}